// Round 12
// baseline (402.412 us; speedup 1.0000x reference)
//
#include <hip/hip_runtime.h>
#include <hip/hip_bf16.h>

// Problem constants
constexpr int NB  = 4;     // batch
constexpr int NS  = 2048;  // sequence
constexpr int NH  = 8;     // heads
constexpr int DM  = 512;   // d_model
constexpr int DKV = 64;    // d_k = d_v
constexpr int HB  = NH * NB; // 32 (h,b) slices

typedef __attribute__((ext_vector_type(8))) short short8;
typedef __attribute__((ext_vector_type(4))) float f32x4;

__device__ inline unsigned short f2bf(float f) {
    unsigned u = __builtin_bit_cast(unsigned, f);
    u = (u + 0x7fffu + ((u >> 16) & 1u)) >> 16;   // RNE, finite inputs
    return (unsigned short)u;
}
__device__ inline float bf2f(unsigned short h) {
    unsigned u = ((unsigned)h) << 16;
    return __builtin_bit_cast(float, u);
}
__device__ inline short8 ld8(const unsigned short* p) { return *(const short8*)p; }

// Load 8 consecutive fp32, convert to bf16x8 fragment
__device__ inline short8 pack8(const float* p) {
    f32x4 a = *(const f32x4*)p;
    f32x4 b = *(const f32x4*)(p + 4);
    short8 r;
    r[0] = (short)f2bf(a[0]); r[1] = (short)f2bf(a[1]);
    r[2] = (short)f2bf(a[2]); r[3] = (short)f2bf(a[3]);
    r[4] = (short)f2bf(b[0]); r[5] = (short)f2bf(b[1]);
    r[6] = (short)f2bf(b[2]); r[7] = (short)f2bf(b[3]);
    return r;
}

__device__ inline f32x4 mfma16(short8 a, short8 b, f32x4 c) {
    return __builtin_amdgcn_mfma_f32_16x16x32_bf16(a, b, c, 0, 0, 0);
}

// async global->LDS, 16 bytes per lane; lds base must be wave-uniform
__device__ inline void gl_lds16(const void* g, void* l) {
    __builtin_amdgcn_global_load_lds(
        (const __attribute__((address_space(1))) unsigned*)g,
        (__attribute__((address_space(3))) unsigned*)l, 16, 0, 0);
}

__device__ inline void bar() { __builtin_amdgcn_s_barrier(); }

// ---------------------------------------------------------------------------
// Convert the four 512x512 fp32 weight matrices to bf16. grid (128, 4).
// ---------------------------------------------------------------------------
__global__ __launch_bounds__(256) void k_cvtw(const float* __restrict__ s0,
                                              const float* __restrict__ s1,
                                              const float* __restrict__ s2,
                                              const float* __restrict__ s3,
                                              unsigned short* __restrict__ d0,
                                              unsigned short* __restrict__ d1,
                                              unsigned short* __restrict__ d2,
                                              unsigned short* __restrict__ d3)
{
    const float* s; unsigned short* d;
    switch (blockIdx.y) {
        case 0:  s = s0; d = d0; break;
        case 1:  s = s1; d = d1; break;
        case 2:  s = s2; d = d2; break;
        default: s = s3; d = d3; break;
    }
    const size_t i = ((size_t)blockIdx.x * 256 + threadIdx.x) * 8;
    *(short8*)(d + i) = pack8(s + i);
}

// ---------------------------------------------------------------------------
// Projections (all three in one launch, z selects q/k/v). X is fp32 (packed
// to bf16 in-loop), W pre-converted bf16.
// z<2: out[hb][s][dkv] (Q scaled by log2e/8, K); z==2: out[hb][dkv][s] (V^T).
// ---------------------------------------------------------------------------
__global__ __launch_bounds__(256, 4) void k_proj3(const float* __restrict__ Xq,
                                                  const float* __restrict__ Xk,
                                                  const float* __restrict__ Xv,
                                                  const unsigned short* __restrict__ Wq,
                                                  const unsigned short* __restrict__ Wk,
                                                  const unsigned short* __restrict__ Wv,
                                                  const float* __restrict__ bq,
                                                  const float* __restrict__ bk,
                                                  const float* __restrict__ bv,
                                                  unsigned short* __restrict__ oq,
                                                  unsigned short* __restrict__ ok,
                                                  unsigned short* __restrict__ ov)
{
    const float* X; const unsigned short* W; const float* bias; unsigned short* out;
    float scale = 1.0f; int vtrans = 0;
    switch (blockIdx.z) {
        case 0:  X = Xq; W = Wq; bias = bq; out = oq;
                 scale = 0.125f * 1.44269504088896340736f; break;
        case 1:  X = Xk; W = Wk; bias = bk; out = ok; break;
        default: X = Xv; W = Wv; bias = bv; out = ov; vtrans = 1; break;
    }
    const int tid = threadIdx.x;
    const int l = tid & 63, w = tid >> 6;
    const int c = l & 15, g = l >> 4;
    const int m0 = blockIdx.y * 64 + w * 16;
    const int f0 = blockIdx.x * 64;
    const int arow = m0 + c;

    f32x4 acc[4] = {};
    const float* aB = X + (size_t)arow * DM;
    for (int kb = 0; kb < DM; kb += 32) {
        short8 af = pack8(aB + kb + g * 8);
#pragma unroll
        for (int n = 0; n < 4; ++n) {
            short8 bf = ld8(W + (size_t)(f0 + n * 16 + c) * DM + kb + g * 8);
            acc[n] = mfma16(af, bf, acc[n]);
        }
    }
#pragma unroll
    for (int n = 0; n < 4; ++n) {
        const int f = f0 + n * 16 + c;
        const int h = f >> 6, d = f & 63;
        const float bvv = bias[f];
#pragma unroll
        for (int r = 0; r < 4; ++r) {
            const int m = m0 + g * 4 + r;
            const int bb = m >> 11, s = m & (NS - 1);
            const int hb = h * NB + bb;
            const float v = (acc[n][r] + bvv) * scale;
            const size_t idx = vtrans ? ((size_t)(hb * DKV + d) * NS + s)
                                      : ((size_t)(hb * NS + s) * DKV + d);
            out[idx] = f2bf(v);
        }
    }
}

// ---------------------------------------------------------------------------
// Fused attention, 32 q-rows per wave (2 sub-tiles share each K/V fragment).
// R10's proven 2-deep / 2-barrier staging schedule (counted vmcnt, never
// waits on stores). Pass 1: l=sum(exp2(s)). Pass 2: attn fp32 stored directly
// from C-fragments; P -> swizzled per-wave LDS for PV. XCD-chunked swizzle.
// launch_bounds(256,2): 512-block grid gives 2 blocks/CU; 256-VGPR headroom.
// ---------------------------------------------------------------------------
__global__ __launch_bounds__(256, 2) void k_attn(const unsigned short* __restrict__ Qh,
                                                 const unsigned short* __restrict__ Kh,
                                                 const unsigned short* __restrict__ Vt,
                                                 float* __restrict__ attn,
                                                 unsigned short* __restrict__ Obuf)
{
    __shared__ __align__(16) char kld[2][8192];    // 64 keys x 64 dims bf16 (swizzled)
    __shared__ __align__(16) char vld[2][8192];    // 64 dims x 64 keys bf16 (swizzled)
    __shared__ __align__(16) char plds[4 * 4096];  // per-wave 32x64 bf16 P tile
    const int tid = threadIdx.x;
    const int l = tid & 63, w = tid >> 6;
    const int c = l & 15, g = l >> 4;
    constexpr int NT = NS / 64;                    // 32 key tiles

    // XCD-chunked swizzle: 512 blocks, 8 XCDs -> 64 consecutive work-ids
    // (4 full hb slices) per XCD.
    const int bid = blockIdx.x;
    const int wid = (bid & 7) * 64 + (bid >> 3);
    const int hb = wid >> 4;
    const int q0 = (wid & 15) * 128 + w * 32;      // this wave's 32 q-rows
    char* myp = plds + w * 4096;

    const char* kbytes = (const char*)(Kh + (size_t)hb * NS * DKV);
    const char* vbytes = (const char*)(Vt + (size_t)hb * DKV * NS);

    short8 qf[2][2];
#pragma unroll
    for (int s2 = 0; s2 < 2; ++s2) {
        const unsigned short* qb = Qh + ((size_t)hb * NS + q0 + s2 * 16 + c) * DKV + g * 8;
        qf[s2][0] = ld8(qb); qf[s2][1] = ld8(qb + 32);
    }

    // staging source offsets (pre-swizzled): issue j covers LDS chunk
    // (w*2+j)*1024 + lane*16; row = chunk_row + (lane>>3), colb = (lane&7)*16.
    int koff[2], voff[2];
#pragma unroll
    for (int j = 0; j < 2; ++j) {
        const int D = (w * 2 + j) * 1024 + l * 16;
        const int row = D >> 7;
        const int scolb = (D & 127) ^ ((row & 7) << 4);
        koff[j] = row * 128 + scolb;               // K rows: 128 B stride in tile
        voff[j] = row * (NS * 2) + scolb;          // V^T rows: 4096 B global stride
    }
    const int swc = (c & 7) << 4;                  // read-side swizzle

    const int ldsbase = w * 2048;                  // this wave's staging chunk base

    // ---- pass 1: row sums of exp2(s), K double-buffered (2-deep, 2-barrier)
    float ls[2][4] = {};
    {
        gl_lds16(kbytes + koff[0], kld[0] + ldsbase);
        gl_lds16(kbytes + koff[1], kld[0] + ldsbase + 1024);
        asm volatile("s_waitcnt vmcnt(0)" ::: "memory");
        bar();                                     // publish tile 0
        __builtin_amdgcn_sched_barrier(0);
        int cur = 0;
        for (int kt = 0; kt < NT; ++kt) {
            if (kt + 1 < NT) {
                const size_t nb = (size_t)(kt + 1) * 64 * 128;
                gl_lds16(kbytes + nb + koff[0], kld[cur ^ 1] + ldsbase);
                gl_lds16(kbytes + nb + koff[1], kld[cur ^ 1] + ldsbase + 1024);
            }
            if (kt > 0) {
                if (kt + 1 < NT) { asm volatile("s_waitcnt vmcnt(2)" ::: "memory"); }
                else             { asm volatile("s_waitcnt vmcnt(0)" ::: "memory"); }
                bar();                             // publish tile kt
                __builtin_amdgcn_sched_barrier(0);
            }
#pragma unroll
            for (int t = 0; t < 4; ++t) {
                const int rb = (t * 16 + c) * 128;
                const short8 b0 = *(const short8*)(kld[cur] + rb + ((g * 16) ^ swc));
                const short8 b1 = *(const short8*)(kld[cur] + rb + ((64 + g * 16) ^ swc));
#pragma unroll
                for (int s2 = 0; s2 < 2; ++s2) {
                    f32x4 z = {};
                    z = mfma16(qf[s2][0], b0, z);
                    z = mfma16(qf[s2][1], b1, z);
#pragma unroll
                    for (int r = 0; r < 4; ++r) ls[s2][r] += exp2f(z[r]);
                }
            }
            bar();                                 // release kld[cur] for overwrite
            cur ^= 1;
        }
    }
    float li[2][4];
#pragma unroll
    for (int s2 = 0; s2 < 2; ++s2)
#pragma unroll
        for (int r = 0; r < 4; ++r) {
            float s = ls[s2][r];
            s += __shfl_xor(s, 1);
            s += __shfl_xor(s, 2);
            s += __shfl_xor(s, 4);
            s += __shfl_xor(s, 8);
            li[s2][r] = 1.0f / s;
        }

    // ---- pass 2
    f32x4 oacc[2][4] = {};
    // direct attn store base: lane covers rows q0 + s2*16 + g*4 + r, col c+t*16
    float* abase = attn + (size_t)hb * NS * NS + (size_t)(q0 + g * 4) * NS + c;

    {
        gl_lds16(kbytes + koff[0], kld[0] + ldsbase);
        gl_lds16(kbytes + koff[1], kld[0] + ldsbase + 1024);
        gl_lds16(vbytes + voff[0], vld[0] + ldsbase);
        gl_lds16(vbytes + voff[1], vld[0] + ldsbase + 1024);
        asm volatile("s_waitcnt vmcnt(0)" ::: "memory");
        bar();                                     // publish tile 0
        __builtin_amdgcn_sched_barrier(0);
        int cur = 0;
        for (int kt = 0; kt < NT; ++kt) {
            const int k0 = kt * 64;
            if (kt + 1 < NT) {
                const size_t nkb = (size_t)(k0 + 64) * 128;
                const size_t nvb = (size_t)(k0 + 64) * 2;
                gl_lds16(kbytes + nkb + koff[0], kld[cur ^ 1] + ldsbase);
                gl_lds16(kbytes + nkb + koff[1], kld[cur ^ 1] + ldsbase + 1024);
                gl_lds16(vbytes + nvb + voff[0], vld[cur ^ 1] + ldsbase);
                gl_lds16(vbytes + nvb + voff[1], vld[cur ^ 1] + ldsbase + 1024);
            }
            if (kt > 0) {
                // queue (old->new): L_kt(4), S_{kt-1}(32), L_{kt+1}(4) = 40.
                // vmcnt(36) drains L_kt only; never waits on stores.
                if (kt + 1 < NT) { asm volatile("s_waitcnt vmcnt(36)" ::: "memory"); }
                else             { asm volatile("s_waitcnt vmcnt(32)" ::: "memory"); }
                bar();                             // publish tile kt
                __builtin_amdgcn_sched_barrier(0);
            }
            // QK^T from K-LDS; K fragments shared across both q sub-tiles
            f32x4 sc[2][4];
#pragma unroll
            for (int t = 0; t < 4; ++t) {
                const int rb = (t * 16 + c) * 128;
                const short8 b0 = *(const short8*)(kld[cur] + rb + ((g * 16) ^ swc));
                const short8 b1 = *(const short8*)(kld[cur] + rb + ((64 + g * 16) ^ swc));
#pragma unroll
                for (int s2 = 0; s2 < 2; ++s2) {
                    f32x4 z = {};
                    z = mfma16(qf[s2][0], b0, z);
                    z = mfma16(qf[s2][1], b1, z);
                    sc[s2][t] = z;
                }
            }
            // normalized P: direct fp32 scalar stores (from fragments) +
            // bf16 -> swizzled per-wave LDS for PV
#pragma unroll
            for (int s2 = 0; s2 < 2; ++s2)
#pragma unroll
                for (int t = 0; t < 4; ++t)
#pragma unroll
                    for (int r = 0; r < 4; ++r) {
                        const float p = exp2f(sc[s2][t][r]) * li[s2][r];
                        abase[(size_t)(s2 * 16 + r) * NS + k0 + t * 16] = p;
                        const int row = s2 * 16 + g * 4 + r;
                        int by = row * 128 + (t * 16 + c) * 2;
                        by ^= (row & 7) << 4;
                        *(unsigned short*)(myp + by) = f2bf(p);
                    }
            asm volatile("s_waitcnt lgkmcnt(0)" ::: "memory");
            __builtin_amdgcn_sched_barrier(0);
            // PV: A-frags of P from wave LDS (per sub-tile), V frags shared
#pragma unroll
            for (int kk = 0; kk < 2; ++kk) {
                const short8 pa0 = *(const short8*)(myp + c * 128 + ((kk * 64 + g * 16) ^ swc));
                const short8 pa1 = *(const short8*)(myp + (16 + c) * 128 + ((kk * 64 + g * 16) ^ swc));
#pragma unroll
                for (int n = 0; n < 4; ++n) {
                    const int rb = (n * 16 + c) * 128;
                    const short8 vb = *(const short8*)(vld[cur] + rb + ((kk * 64 + g * 16) ^ swc));
                    oacc[0][n] = mfma16(pa0, vb, oacc[0][n]);
                    oacc[1][n] = mfma16(pa1, vb, oacc[1][n]);
                }
            }
            bar();                                 // release buf[cur] for overwrite
            cur ^= 1;
        }
    }

    const int h = hb >> 2, bb = hb & 3;
#pragma unroll
    for (int s2 = 0; s2 < 2; ++s2)
#pragma unroll
        for (int n = 0; n < 4; ++n)
#pragma unroll
            for (int r = 0; r < 4; ++r) {
                const int q = q0 + s2 * 16 + g * 4 + r;
                const int dv = n * 16 + c;
                Obuf[((size_t)(bb * NS + q)) * DM + h * DKV + dv] = f2bf(oacc[s2][n][r]);
            }
}

// ---------------------------------------------------------------------------
// FC: Y[m][d] = sum_f O[m][f]*Wfc[d][f] + bfc[d] + resid[m][d], bf16 out.
// ---------------------------------------------------------------------------
__global__ __launch_bounds__(256, 4) void k_fc(const unsigned short* __restrict__ O,
                                            const unsigned short* __restrict__ Wfc,
                                            const float* __restrict__ bfc,
                                            const float* __restrict__ resid,
                                            unsigned short* __restrict__ Y)
{
    const int tid = threadIdx.x;
    const int l = tid & 63, w = tid >> 6;
    const int c = l & 15, g = l >> 4;
    const int m0 = blockIdx.y * 64 + w * 16;
    const int f0 = blockIdx.x * 64;
    const int arow = m0 + c;

    f32x4 acc[4] = {};
    const unsigned short* aB = O + (size_t)arow * DM;
    for (int kb = 0; kb < DM; kb += 32) {
        short8 af = ld8(aB + kb + g * 8);
#pragma unroll
        for (int n = 0; n < 4; ++n) {
            short8 bf = ld8(Wfc + (size_t)(f0 + n * 16 + c) * DM + kb + g * 8);
            acc[n] = mfma16(af, bf, acc[n]);
        }
    }
#pragma unroll
    for (int n = 0; n < 4; ++n) {
        const int d = f0 + n * 16 + c;
        const float bv = bfc[d];
#pragma unroll
        for (int r = 0; r < 4; ++r) {
            const int m = m0 + g * 4 + r;
            const float v = acc[n][r] + bv + resid[(size_t)m * DM + d];
            Y[(size_t)m * DM + d] = f2bf(v);
        }
    }
}

// ---------------------------------------------------------------------------
// LayerNorm: one wave per row of 512.
// ---------------------------------------------------------------------------
__global__ __launch_bounds__(256) void k_ln(const unsigned short* __restrict__ Y,
                                            const float* __restrict__ gam,
                                            const float* __restrict__ bet,
                                            float* __restrict__ out)
{
    const int tid = threadIdx.x;
    const int l = tid & 63, w = tid >> 6;
    const int row = blockIdx.x * 4 + w;

    const short8 yv = ld8(Y + (size_t)row * DM + l * 8);
    float x[8];
#pragma unroll
    for (int j = 0; j < 8; ++j) x[j] = bf2f((unsigned short)yv[j]);

    float s = 0.f;
#pragma unroll
    for (int j = 0; j < 8; ++j) s += x[j];
#pragma unroll
    for (int mask = 1; mask <= 32; mask <<= 1) s += __shfl_xor(s, mask);
    const float mean = s * (1.0f / DM);

    float d2 = 0.f;
#pragma unroll
    for (int j = 0; j < 8; ++j) { const float t = x[j] - mean; d2 += t * t; }
#pragma unroll
    for (int mask = 1; mask <= 32; mask <<= 1) d2 += __shfl_xor(d2, mask);
    const float rstd = rsqrtf(d2 * (1.0f / DM) + 1e-5f);

#pragma unroll
    for (int j = 0; j < 8; ++j) {
        const int d = l * 8 + j;
        out[(size_t)row * DM + d] = (x[j] - mean) * rstd * gam[d] + bet[d];
    }
}

// ---------------------------------------------------------------------------
extern "C" void kernel_launch(void* const* d_in, const int* in_sizes, int n_in,
                              void* d_out, int out_size, void* d_ws, size_t ws_size,
                              hipStream_t stream)
{
    const float* q    = (const float*)d_in[0];
    const float* k    = (const float*)d_in[1];
    const float* v    = (const float*)d_in[2];
    const float* w_qs = (const float*)d_in[3];
    const float* b_qs = (const float*)d_in[4];
    const float* w_ks = (const float*)d_in[5];
    const float* b_ks = (const float*)d_in[6];
    const float* w_vs = (const float*)d_in[7];
    const float* b_vs = (const float*)d_in[8];
    const float* w_fc = (const float*)d_in[9];
    const float* b_fc = (const float*)d_in[10];
    const float* ln_g = (const float*)d_in[11];
    const float* ln_b = (const float*)d_in[12];

    char* ws = (char*)d_ws;
    unsigned short* Qh = (unsigned short*)(ws);                    //  8 MB bf16 [hb][s][64], scaled log2e/8
    unsigned short* Kh = (unsigned short*)(ws + (8u  << 20));      //  8 MB bf16 [hb][s][64]
    unsigned short* Vt = (unsigned short*)(ws + (16u << 20));      //  8 MB bf16 [hb][64][s]
    unsigned short* Ob = (unsigned short*)(ws + (24u << 20));      //  8 MB bf16 [m][512]
    unsigned short* Yb = (unsigned short*)(ws + (32u << 20));      //  8 MB bf16 [m][512]
    unsigned short* Wq = (unsigned short*)(ws + (40u << 20));      // 512 KB bf16 each
    unsigned short* Wk = Wq + (size_t)DM * DM;
    unsigned short* Wv = Wk + (size_t)DM * DM;
    unsigned short* Wf = Wv + (size_t)DM * DM;

    float* xout = (float*)d_out;
    float* attn = xout + (size_t)NB * NS * DM;  // output 1 region

    k_cvtw<<<dim3(128, 4), 256, 0, stream>>>(w_qs, w_ks, w_vs, w_fc, Wq, Wk, Wv, Wf);

    k_proj3<<<dim3(8, 128, 3), 256, 0, stream>>>(q, k, v, Wq, Wk, Wv,
                                                 b_qs, b_ks, b_vs, Qh, Kh, Vt);

    k_attn<<<512, 256, 0, stream>>>(Qh, Kh, Vt, attn, Ob);

    k_fc<<<dim3(8, 128), 256, 0, stream>>>(Ob, Wf, b_fc, q, Yb);
    k_ln<<<NB * NS / 4, 256, 0, stream>>>(Yb, ln_g, ln_b, xout);
}